// Round 11
// baseline (512.740 us; speedup 1.0000x reference)
//
#include <hip/hip_runtime.h>
#include <stdint.h>

#define D_FEAT 256
#define NGRAPH 64
#define NSPLIT 8
#define BM 128
#define BK 32
#define LDR 40   // LDS row stride in bf16 elems
#define SCAN_CHUNK 1024

using f32x4 = __attribute__((ext_vector_type(4))) float;
using s16x8 = __attribute__((ext_vector_type(8))) short;
using s16x4 = __attribute__((ext_vector_type(4))) short;
using i32x4 = __attribute__((ext_vector_type(4))) int;

__device__ __forceinline__ unsigned short f2bf(float f) {
  union { float f; unsigned u; } v; v.f = f;
  return (unsigned short)((v.u + 0x7FFFu + ((v.u >> 16) & 1u)) >> 16);  // RNE
}
__device__ __forceinline__ float bf2f(unsigned short h) {
  union { unsigned u; float f; } v; v.u = ((unsigned)h) << 16; return v.f;
}

// ---------- CSR build ----------
__global__ void hist_k(const int* __restrict__ dst, int* __restrict__ counts, int E) {
  int e = blockIdx.x * blockDim.x + threadIdx.x;
  if (e < E) atomicAdd(&counts[dst[e]], 1);
}

// Phase A: per-block (1024-elem chunk) sums of counts padded to multiple of 4
__global__ __launch_bounds__(256) void bsum_k(const int* __restrict__ counts,
                                              int* __restrict__ bsum, int N) {
  int base = blockIdx.x * SCAN_CHUNK;
  int t = threadIdx.x;
  int idx = base + t * 4;
  int s = 0;
  for (int j = 0; j < 4; ++j) {
    if (idx + j < N) { int c = counts[idx + j]; s += (c + 3) & ~3; }
  }
  for (int d = 1; d < 64; d <<= 1) s += __shfl_xor(s, d);
  __shared__ int ws[4];
  if ((t & 63) == 0) ws[t >> 6] = s;
  __syncthreads();
  if (t == 0) bsum[blockIdx.x] = ws[0] + ws[1] + ws[2] + ws[3];
}

// Phase B: scan the block sums (nb <= 1024), write total to offN
__global__ __launch_bounds__(1024) void bscan_k(const int* __restrict__ bsum,
                                                int* __restrict__ boff,
                                                int* __restrict__ offN, int nb) {
  __shared__ int part[1024];
  int t = threadIdx.x;
  int v = (t < nb) ? bsum[t] : 0;
  part[t] = v;
  __syncthreads();
  for (int d = 1; d < 1024; d <<= 1) {
    int u = (t >= d) ? part[t - d] : 0;
    __syncthreads();
    part[t] += u;
    __syncthreads();
  }
  if (t < nb) boff[t] = part[t] - v;
  if (t == 1023) offN[0] = part[1023];
}

// Phase C: in-block scan (padded counts) + block offset -> off/cur/isd
__global__ __launch_bounds__(256) void fillscan_k(const int* __restrict__ counts,
                                                  const int* __restrict__ boff,
                                                  int* __restrict__ off, int* __restrict__ cur,
                                                  float* __restrict__ isd, int N) {
  int b = blockIdx.x;
  int base = b * SCAN_CHUNK;
  int t = threadIdx.x;
  int idx = base + t * 4;
  int c[4], cp[4];
  int s = 0;
  for (int j = 0; j < 4; ++j) {
    c[j] = (idx + j < N) ? counts[idx + j] : 0;
    cp[j] = (c[j] + 3) & ~3;
    s += cp[j];
  }
  int inc = s;
  int lane = t & 63;
  for (int d = 1; d < 64; d <<= 1) {
    int u = __shfl_up(inc, d);
    if (lane >= d) inc += u;
  }
  __shared__ int wtot[4];
  if (lane == 63) wtot[t >> 6] = inc;
  __syncthreads();
  int woff = 0;
  for (int w = 0; w < (t >> 6); ++w) woff += wtot[w];
  int ex = boff[b] + woff + inc - s;
  for (int j = 0; j < 4; ++j) {
    int i = idx + j;
    if (i < N) {
      off[i] = ex;
      cur[i] = ex;
      isd[i] = rsqrtf((float)(c[j] + 1));  // real degree + self-loop
      ex += cp[j];
    }
  }
}

__global__ void fill_k(const int* __restrict__ src, const int* __restrict__ dst,
                       int* __restrict__ cur, int* __restrict__ csr, int E) {
  int e = blockIdx.x * blockDim.x + threadIdx.x;
  if (e < E) {
    int d = dst[e];
    int pos = atomicAdd(&cur[d], 1);
    csr[pos] = src[e];
  }
}

// pad slots + prefetch slack get sentinel N; zero P/H sentinel rows
__global__ __launch_bounds__(256) void padfix_k(const int* __restrict__ counts,
                                                const int* __restrict__ off,
                                                int* __restrict__ csr,
                                                unsigned int* __restrict__ Pu,
                                                unsigned int* __restrict__ Hu,
                                                int NP1, int N) {
  int i = blockIdx.x * blockDim.x + threadIdx.x;
  if (i < N) {
    int c = counts[i];
    int base = off[i] + c;
    int pad = ((c + 3) & ~3) - c;
    for (int j = 0; j < pad; ++j) csr[base + j] = N;
  }
  if (i == N) {
    int e0 = off[N];
    for (int j = 0; j < 64; ++j) csr[e0 + j] = N;  // 8-wide prefetch slack
  }
  if (blockIdx.x == 0) {
    int j = threadIdx.x;
    if (j < 128) {
      Pu[((size_t)(j >> 4) * NP1 + N) * 16 + (j & 15)] = 0u;
    } else {
      int j2 = j - 128;
      Hu[((size_t)(j2 >> 4) * NP1 + N) * 16 + (j2 & 15)] = 0u;
    }
  }
}

// ---------- weight convert: W[k][n] f32 -> Wt[n][k] bf16 ----------
__global__ void wconv_k(const float* __restrict__ W0, const float* __restrict__ W1,
                        const float* __restrict__ W2, unsigned short* __restrict__ Wt) {
  int idx = blockIdx.x * blockDim.x + threadIdx.x;  // 0 .. 3*65536
  int w = idx >> 16; int r = idx & 65535;
  int k = r >> 8, n = r & 255;
  const float* W = (w == 0) ? W0 : (w == 1) ? W1 : W2;
  Wt[(size_t)w * 65536 + n * 256 + k] = f2bf(W[k * 256 + n]);
}

// ---------- GEMM: P[slice-major] = bf16((X @ W) * isd), 128x256 tile ----------
// slice-major: elem(s, node, w) = ((size_t)s*NP1 + node)*32 + w, s=col>>5, w=col&31
// 4 waves; wave w owns 64-col quadrant x all 128 rows: acc[8][4], 32 MFMA/k0.
template <bool F32IN>
__global__ __launch_bounds__(256) void gemm_k(const void* __restrict__ Xv,
                                              const unsigned short* __restrict__ Wt,
                                              unsigned short* __restrict__ P,
                                              const float* __restrict__ isd, int M, int NP1) {
  __shared__ __align__(16) short As[BM * LDR];       // 10240 B
  __shared__ __align__(16) short Bs[D_FEAT * LDR];   // 20480 B
  int t = threadIdx.x;
  int lane = t & 63;
  int wave = t >> 6;              // 0..3 -> 64-col quadrant
  int row0 = blockIdx.x * BM;
  int l15 = lane & 15;
  int l4  = lane >> 4;

  f32x4 acc[8][4];
  for (int m = 0; m < 8; ++m)
    for (int n = 0; n < 4; ++n)
      acc[m][n] = (f32x4){0.f, 0.f, 0.f, 0.f};

  for (int k0 = 0; k0 < D_FEAT; k0 += BK) {
    if constexpr (F32IN) {
      const float* X = (const float*)Xv;   // row-major f32 input
      for (int i = 0; i < 4; ++i) {
        int g = t + i * 256;            // 0..1023
        int r = g >> 3, c4 = g & 7;
        int grow = row0 + r;
        f32x4 v = (f32x4){0.f, 0.f, 0.f, 0.f};
        if (grow < M) v = *(const f32x4*)(X + (size_t)grow * D_FEAT + k0 + c4 * 4);
        s16x4 b;
        b.x = (short)f2bf(v.x); b.y = (short)f2bf(v.y);
        b.z = (short)f2bf(v.z); b.w = (short)f2bf(v.w);
        *(s16x4*)&As[r * LDR + c4 * 4] = b;
      }
    } else {
      // slice-major bf16 input: k-range [k0,k0+32) == slice k0>>5
      const unsigned short* X = (const unsigned short*)Xv;
      for (int i = 0; i < 2; ++i) {
        int g = t + i * 256;            // 0..511
        int r = g >> 2, c = g & 3;      // 128 rows x 4 chunks of 8 bf16
        int grow = row0 + r;
        s16x8 v = {0, 0, 0, 0, 0, 0, 0, 0};
        if (grow < M) v = *(const s16x8*)(X + ((size_t)(k0 >> 5) * NP1 + grow) * 32 + c * 8);
        *(s16x8*)&As[r * LDR + c * 8] = v;
      }
    }
    // stage B: Wt rows (already [n][k] bf16), 256 rows x 32 k
    for (int i = 0; i < 4; ++i) {
      int g = t + i * 256;            // 0..1023
      int n = g >> 2, c = g & 3;
      i32x4 v = *(const i32x4*)(Wt + (size_t)n * D_FEAT + k0 + c * 8);
      *(i32x4*)&Bs[n * LDR + c * 8] = v;
    }
    __syncthreads();
    s16x8 a[8], b[4];
    for (int m = 0; m < 8; ++m)
      a[m] = *(const s16x8*)&As[(m * 16 + l15) * LDR + l4 * 8];
    for (int n = 0; n < 4; ++n)
      b[n] = *(const s16x8*)&Bs[(wave * 64 + n * 16 + l15) * LDR + l4 * 8];
    for (int m = 0; m < 8; ++m)
      for (int n = 0; n < 4; ++n)
        acc[m][n] = __builtin_amdgcn_mfma_f32_16x16x32_bf16(a[m], b[n], acc[m][n], 0, 0, 0);
    __syncthreads();
  }

  // epilogue: C/D layout col=lane&15, row=4*(lane>>4)+reg ; write slice-major
  for (int m = 0; m < 8; ++m) {
    int rbase = row0 + m * 16 + l4 * 4;
    for (int r = 0; r < 4; ++r) {
      int row = rbase + r;
      if (row >= M) continue;
      float sc = isd[row];
      for (int n = 0; n < 4; ++n) {
        int col = wave * 64 + n * 16 + l15;
        P[((size_t)(col >> 5) * NP1 + row) * 32 + (col & 31)] = f2bf(acc[m][n][r] * sc);
      }
    }
  }
}

// ---------- aggregation, XCD-sliced, group-per-node, 8-wide ILP (r10 known-good) ----------
__global__ __launch_bounds__(256) void agg_k(const unsigned short* __restrict__ P,
                                             const int* __restrict__ csr,
                                             const int* __restrict__ off,
                                             const float* __restrict__ isd,
                                             const float* __restrict__ bias,
                                             unsigned short* __restrict__ H,
                                             int N, int NP1) {
  int s = blockIdx.x & 7;
  int node = (blockIdx.x >> 3) * 64 + (threadIdx.x >> 2);
  if (node >= N) return;
  int c = threadIdx.x & 3;    // 16B chunk within 64B slice row
  const s16x8* Pb = (const s16x8*)P + (size_t)s * NP1 * 4;

  int lo = off[node], hi = off[node + 1];
  float sc = isd[node];

  float acc[8];
  {
    s16x8 v = Pb[(size_t)node * 4 + c];   // self-loop term
    for (int j = 0; j < 8; ++j) acc[j] = bf2f((unsigned short)v[j]);
  }

  int e = lo;
  if (e + 8 <= hi) {
    i32x4 ia = __builtin_nontemporal_load((const i32x4*)(csr + e));
    i32x4 ib = __builtin_nontemporal_load((const i32x4*)(csr + e + 4));
    for (; e + 8 <= hi; e += 8) {
      i32x4 na = __builtin_nontemporal_load((const i32x4*)(csr + e + 8));   // slack-padded
      i32x4 nb = __builtin_nontemporal_load((const i32x4*)(csr + e + 12));
      s16x8 v0 = Pb[(size_t)ia.x * 4 + c];
      s16x8 v1 = Pb[(size_t)ia.y * 4 + c];
      s16x8 v2 = Pb[(size_t)ia.z * 4 + c];
      s16x8 v3 = Pb[(size_t)ia.w * 4 + c];
      s16x8 v4 = Pb[(size_t)ib.x * 4 + c];
      s16x8 v5 = Pb[(size_t)ib.y * 4 + c];
      s16x8 v6 = Pb[(size_t)ib.z * 4 + c];
      s16x8 v7 = Pb[(size_t)ib.w * 4 + c];
      for (int j = 0; j < 8; ++j) acc[j] += bf2f((unsigned short)v0[j]);
      for (int j = 0; j < 8; ++j) acc[j] += bf2f((unsigned short)v1[j]);
      for (int j = 0; j < 8; ++j) acc[j] += bf2f((unsigned short)v2[j]);
      for (int j = 0; j < 8; ++j) acc[j] += bf2f((unsigned short)v3[j]);
      for (int j = 0; j < 8; ++j) acc[j] += bf2f((unsigned short)v4[j]);
      for (int j = 0; j < 8; ++j) acc[j] += bf2f((unsigned short)v5[j]);
      for (int j = 0; j < 8; ++j) acc[j] += bf2f((unsigned short)v6[j]);
      for (int j = 0; j < 8; ++j) acc[j] += bf2f((unsigned short)v7[j]);
      ia = na; ib = nb;
    }
  }
  if (e < hi) {  // exactly one padded 4-group remains
    i32x4 idx = __builtin_nontemporal_load((const i32x4*)(csr + e));
    s16x8 v0 = Pb[(size_t)idx.x * 4 + c];
    s16x8 v1 = Pb[(size_t)idx.y * 4 + c];
    s16x8 v2 = Pb[(size_t)idx.z * 4 + c];
    s16x8 v3 = Pb[(size_t)idx.w * 4 + c];
    for (int j = 0; j < 8; ++j) acc[j] += bf2f((unsigned short)v0[j]);
    for (int j = 0; j < 8; ++j) acc[j] += bf2f((unsigned short)v1[j]);
    for (int j = 0; j < 8; ++j) acc[j] += bf2f((unsigned short)v2[j]);
    for (int j = 0; j < 8; ++j) acc[j] += bf2f((unsigned short)v3[j]);
  }

  const float* bp = bias + s * 32 + c * 8;
  f32x4 b0 = *(const f32x4*)bp;
  f32x4 b1 = *(const f32x4*)(bp + 4);
  s16x8 o;
  o[0] = (short)f2bf(fmaxf(acc[0] * sc + b0.x, 0.f));
  o[1] = (short)f2bf(fmaxf(acc[1] * sc + b0.y, 0.f));
  o[2] = (short)f2bf(fmaxf(acc[2] * sc + b0.z, 0.f));
  o[3] = (short)f2bf(fmaxf(acc[3] * sc + b0.w, 0.f));
  o[4] = (short)f2bf(fmaxf(acc[4] * sc + b1.x, 0.f));
  o[5] = (short)f2bf(fmaxf(acc[5] * sc + b1.y, 0.f));
  o[6] = (short)f2bf(fmaxf(acc[6] * sc + b1.z, 0.f));
  o[7] = (short)f2bf(fmaxf(acc[7] * sc + b1.w, 0.f));
  __builtin_nontemporal_store(o, (s16x8*)H + ((size_t)s * NP1 + node) * 4 + c);
}

// ---------- pooling (slice-major H) ----------
__device__ __forceinline__ int lower_bound_batch(const int* __restrict__ b, int N, int v) {
  int lo = 0, hi = N;
  while (lo < hi) { int mid = (lo + hi) >> 1; if (b[mid] < v) lo = mid + 1; else hi = mid; }
  return lo;
}

__global__ __launch_bounds__(256) void pool_k(const unsigned short* __restrict__ H,
                                              const int* __restrict__ batch,
                                              float* __restrict__ pp, int N, int NP1) {
  int g = blockIdx.x >> 3;
  int s = blockIdx.x & (NSPLIT - 1);
  int cf = threadIdx.x;  // feature 0..255
  const unsigned short* Hs = H + (size_t)(cf >> 5) * NP1 * 32 + (cf & 31);
  int lo = lower_bound_batch(batch, N, g);
  int hi = lower_bound_batch(batch, N, g + 1);
  int len = hi - lo;
  int slo = lo + (int)(((long long)len * s) >> 3);
  int shi = lo + (int)(((long long)len * (s + 1)) >> 3);
  float sum = 0.f;
  for (int i = slo; i < shi; ++i) sum += bf2f(Hs[(size_t)i * 32]);
  pp[(g * NSPLIT + s) * D_FEAT + cf] = sum;
}

// ---------- FC head ----------
__global__ __launch_bounds__(256) void fc_k(const float* __restrict__ pp,
                                            const int* __restrict__ batch,
                                            const float* __restrict__ fc1w, const float* __restrict__ fc1b,
                                            const float* __restrict__ fc2w, const float* __restrict__ fc2b,
                                            float* __restrict__ out, int N) {
  __shared__ float pl[D_FEAT];
  __shared__ float h1[D_FEAT];
  int g = blockIdx.x, j = threadIdx.x;
  int lo = lower_bound_batch(batch, N, g);
  int hi = lower_bound_batch(batch, N, g + 1);
  float cnt = fmaxf((float)(hi - lo), 1.f);
  float sum = 0.f;
  for (int s = 0; s < NSPLIT; ++s) sum += pp[(g * NSPLIT + s) * D_FEAT + j];
  pl[j] = sum / cnt;
  __syncthreads();
  float a = fc1b[j];
  for (int k = 0; k < D_FEAT; ++k) a += pl[k] * fc1w[k * D_FEAT + j];
  h1[j] = fmaxf(a, 0.f);
  __syncthreads();
  if (j < 128) {
    float o = fc2b[j];
    for (int k = 0; k < D_FEAT; ++k) o += h1[k] * fc2w[k * 128 + j];
    out[g * 128 + j] = o;
  }
}

extern "C" void kernel_launch(void* const* d_in, const int* in_sizes, int n_in,
                              void* d_out, int out_size, void* d_ws, size_t ws_size,
                              hipStream_t stream) {
  const float* x    = (const float*)d_in[0];
  const int*   ei   = (const int*)d_in[1];
  const int*   batch= (const int*)d_in[2];
  const float* W0   = (const float*)d_in[3];
  const float* b0   = (const float*)d_in[4];
  const float* W1   = (const float*)d_in[5];
  const float* b1   = (const float*)d_in[6];
  const float* W2   = (const float*)d_in[7];
  const float* b2   = (const float*)d_in[8];
  const float* fc1w = (const float*)d_in[9];
  const float* fc1b = (const float*)d_in[10];
  const float* fc2w = (const float*)d_in[11];
  const float* fc2b = (const float*)d_in[12];
  float* out = (float*)d_out;

  int N = in_sizes[0] / D_FEAT;   // 50000
  int E = in_sizes[1] / 2;        // 800000
  const int* srcE = ei;
  const int* dstE = ei + E;
  int nb = (N + SCAN_CHUNK - 1) / SCAN_CHUNK;  // 49
  int NP1 = N + 1;                 // +1 sentinel row per slice
  int csize = E + 3 * N + 64;      // padded CSR upper bound + 8-wide prefetch slack

  // workspace carve
  char* w = (char*)d_ws;
  auto alloc = [&](size_t bytes) { char* p = w; w += (bytes + 255) & ~(size_t)255; return p; };
  int*   counts = (int*)  alloc((size_t)N * 4);
  int*   off    = (int*)  alloc((size_t)(N + 1) * 4);
  int*   cur    = (int*)  alloc((size_t)N * 4);
  float* isd    = (float*)alloc((size_t)N * 4);
  int*   csr    = (int*)  alloc((size_t)csize * 4);
  int*   bsum   = (int*)  alloc((size_t)nb * 4);
  int*   boff   = (int*)  alloc((size_t)nb * 4);
  unsigned short* Wt = (unsigned short*)alloc((size_t)3 * 65536 * 2);
  unsigned short* P = (unsigned short*)alloc((size_t)NP1 * D_FEAT * 2);  // slice-major
  unsigned short* H = (unsigned short*)alloc((size_t)NP1 * D_FEAT * 2);  // slice-major
  float* pp     = (float*)alloc((size_t)NGRAPH * NSPLIT * D_FEAT * 4);

  hipMemsetAsync(counts, 0, (size_t)N * 4, stream);
  hist_k<<<(E + 255) / 256, 256, 0, stream>>>(dstE, counts, E);
  bsum_k<<<nb, 256, 0, stream>>>(counts, bsum, N);
  bscan_k<<<1, 1024, 0, stream>>>(bsum, boff, off + N, nb);
  fillscan_k<<<nb, 256, 0, stream>>>(counts, boff, off, cur, isd, N);
  fill_k<<<(E + 255) / 256, 256, 0, stream>>>(srcE, dstE, cur, csr, E);
  padfix_k<<<(N + 256) / 256, 256, 0, stream>>>(counts, off, csr,
      (unsigned int*)P, (unsigned int*)H, NP1, N);
  wconv_k<<<768, 256, 0, stream>>>(W0, W1, W2, Wt);

  int gblocks = (N + BM - 1) / BM;
  int ablocks = 8 * ((N + 63) / 64);

  gemm_k<true> <<<gblocks, 256, 0, stream>>>(x, Wt,             P, isd, N, NP1);
  agg_k        <<<ablocks, 256, 0, stream>>>(P, csr, off, isd, b0, H, N, NP1);
  gemm_k<false><<<gblocks, 256, 0, stream>>>(H, Wt + 65536,     P, isd, N, NP1);
  agg_k        <<<ablocks, 256, 0, stream>>>(P, csr, off, isd, b1, H, N, NP1);
  gemm_k<false><<<gblocks, 256, 0, stream>>>(H, Wt + 2 * 65536, P, isd, N, NP1);
  agg_k        <<<ablocks, 256, 0, stream>>>(P, csr, off, isd, b2, H, N, NP1);

  pool_k<<<NGRAPH * NSPLIT, 256, 0, stream>>>(H, batch, pp, N, NP1);
  fc_k  <<<NGRAPH, 256, 0, stream>>>(pp, batch, fc1w, fc1b, fc2w, fc2b, out, N);
}

// Round 12
// 457.370 us; speedup vs baseline: 1.1211x; 1.1211x over previous
//
#include <hip/hip_runtime.h>
#include <stdint.h>

#define D_FEAT 256
#define NGRAPH 64
#define NSPLIT 8
#define BM 64
#define BK 32
#define LDR 40   // LDS row stride for A in bf16 elems
#define SCAN_CHUNK 1024

using f32x4 = __attribute__((ext_vector_type(4))) float;
using s16x8 = __attribute__((ext_vector_type(8))) short;
using s16x4 = __attribute__((ext_vector_type(4))) short;
using i32x4 = __attribute__((ext_vector_type(4))) int;

__device__ __forceinline__ unsigned short f2bf(float f) {
  union { float f; unsigned u; } v; v.f = f;
  return (unsigned short)((v.u + 0x7FFFu + ((v.u >> 16) & 1u)) >> 16);  // RNE
}
__device__ __forceinline__ float bf2f(unsigned short h) {
  union { unsigned u; float f; } v; v.u = ((unsigned)h) << 16; return v.f;
}

// async global->LDS, 16B per lane; dst is wave-uniform base (HW adds lane*16)
__device__ __forceinline__ void gload_lds16(const void* g, void* l) {
  __builtin_amdgcn_global_load_lds(
      (const __attribute__((address_space(1))) unsigned int*)g,
      (__attribute__((address_space(3))) unsigned int*)l, 16, 0, 0);
}

// ---------- CSR build ----------
__global__ void hist_k(const int* __restrict__ dst, int* __restrict__ counts, int E) {
  int e = blockIdx.x * blockDim.x + threadIdx.x;
  if (e < E) atomicAdd(&counts[dst[e]], 1);
}

// Phase A: per-block (1024-elem chunk) sums of counts padded to multiple of 4
__global__ __launch_bounds__(256) void bsum_k(const int* __restrict__ counts,
                                              int* __restrict__ bsum, int N) {
  int base = blockIdx.x * SCAN_CHUNK;
  int t = threadIdx.x;
  int idx = base + t * 4;
  int s = 0;
  for (int j = 0; j < 4; ++j) {
    if (idx + j < N) { int c = counts[idx + j]; s += (c + 3) & ~3; }
  }
  for (int d = 1; d < 64; d <<= 1) s += __shfl_xor(s, d);
  __shared__ int ws[4];
  if ((t & 63) == 0) ws[t >> 6] = s;
  __syncthreads();
  if (t == 0) bsum[blockIdx.x] = ws[0] + ws[1] + ws[2] + ws[3];
}

// Phase B: scan the block sums (nb <= 1024), write total to offN
__global__ __launch_bounds__(1024) void bscan_k(const int* __restrict__ bsum,
                                                int* __restrict__ boff,
                                                int* __restrict__ offN, int nb) {
  __shared__ int part[1024];
  int t = threadIdx.x;
  int v = (t < nb) ? bsum[t] : 0;
  part[t] = v;
  __syncthreads();
  for (int d = 1; d < 1024; d <<= 1) {
    int u = (t >= d) ? part[t - d] : 0;
    __syncthreads();
    part[t] += u;
    __syncthreads();
  }
  if (t < nb) boff[t] = part[t] - v;
  if (t == 1023) offN[0] = part[1023];
}

// Phase C: in-block scan (padded counts) + block offset -> off/cur/isd
__global__ __launch_bounds__(256) void fillscan_k(const int* __restrict__ counts,
                                                  const int* __restrict__ boff,
                                                  int* __restrict__ off, int* __restrict__ cur,
                                                  float* __restrict__ isd, int N) {
  int b = blockIdx.x;
  int base = b * SCAN_CHUNK;
  int t = threadIdx.x;
  int idx = base + t * 4;
  int c[4], cp[4];
  int s = 0;
  for (int j = 0; j < 4; ++j) {
    c[j] = (idx + j < N) ? counts[idx + j] : 0;
    cp[j] = (c[j] + 3) & ~3;
    s += cp[j];
  }
  int inc = s;
  int lane = t & 63;
  for (int d = 1; d < 64; d <<= 1) {
    int u = __shfl_up(inc, d);
    if (lane >= d) inc += u;
  }
  __shared__ int wtot[4];
  if (lane == 63) wtot[t >> 6] = inc;
  __syncthreads();
  int woff = 0;
  for (int w = 0; w < (t >> 6); ++w) woff += wtot[w];
  int ex = boff[b] + woff + inc - s;
  for (int j = 0; j < 4; ++j) {
    int i = idx + j;
    if (i < N) {
      off[i] = ex;
      cur[i] = ex;
      isd[i] = rsqrtf((float)(c[j] + 1));  // real degree + self-loop
      ex += cp[j];
    }
  }
}

__global__ void fill_k(const int* __restrict__ src, const int* __restrict__ dst,
                       int* __restrict__ cur, int* __restrict__ csr, int E) {
  int e = blockIdx.x * blockDim.x + threadIdx.x;
  if (e < E) {
    int d = dst[e];
    int pos = atomicAdd(&cur[d], 1);
    csr[pos] = src[e];
  }
}

// pad slots + prefetch slack get sentinel N; zero P/H sentinel rows
__global__ __launch_bounds__(256) void padfix_k(const int* __restrict__ counts,
                                                const int* __restrict__ off,
                                                int* __restrict__ csr,
                                                unsigned int* __restrict__ Pu,
                                                unsigned int* __restrict__ Hu,
                                                int NP1, int N) {
  int i = blockIdx.x * blockDim.x + threadIdx.x;
  if (i < N) {
    int c = counts[i];
    int base = off[i] + c;
    int pad = ((c + 3) & ~3) - c;
    for (int j = 0; j < pad; ++j) csr[base + j] = N;
  }
  if (i == N) {
    int e0 = off[N];
    for (int j = 0; j < 64; ++j) csr[e0 + j] = N;  // 8-wide prefetch slack
  }
  if (blockIdx.x == 0) {
    int j = threadIdx.x;
    if (j < 128) {
      Pu[((size_t)(j >> 4) * NP1 + N) * 16 + (j & 15)] = 0u;
    } else {
      int j2 = j - 128;
      Hu[((size_t)(j2 >> 4) * NP1 + N) * 16 + (j2 & 15)] = 0u;
    }
  }
}

// ---------- weight convert: W[k][n] f32 -> Wt[n][k] bf16 ----------
__global__ void wconv_k(const float* __restrict__ W0, const float* __restrict__ W1,
                        const float* __restrict__ W2, unsigned short* __restrict__ Wt) {
  int idx = blockIdx.x * blockDim.x + threadIdx.x;  // 0 .. 3*65536
  int w = idx >> 16; int r = idx & 65535;
  int k = r >> 8, n = r & 255;
  const float* W = (w == 0) ? W0 : (w == 1) ? W1 : W2;
  Wt[(size_t)w * 65536 + n * 256 + k] = f2bf(W[k * 256 + n]);
}

// ---------- GEMM: P[slice-major] = bf16((X @ W) * isd), 64x256 tile ----------
// B staged async via global_load_lds into linear LDS [n][64B]; XOR chunk-swizzle
// baked into the per-lane GLOBAL source (rule #21), read back with p = l4^(row&3).
template <bool F32IN>
__global__ __launch_bounds__(256) void gemm_k(const void* __restrict__ Xv,
                                              const unsigned short* __restrict__ Wt,
                                              unsigned short* __restrict__ P,
                                              const float* __restrict__ isd, int M, int NP1) {
  __shared__ __align__(16) short As[BM * LDR];       // 5120 B (padded, reg-staged)
  __shared__ __align__(16) short Bs[D_FEAT * 32];    // 16384 B linear (gload_lds dest)
  int t = threadIdx.x;
  int lane = t & 63;
  int wave = t >> 6;              // 0..3 -> 64-col quadrant
  int row0 = blockIdx.x * BM;
  int l15 = lane & 15;
  int l4  = lane >> 4;

  f32x4 acc[4][4];
  for (int m = 0; m < 4; ++m)
    for (int n = 0; n < 4; ++n)
      acc[m][n] = (f32x4){0.f, 0.f, 0.f, 0.f};

  for (int k0 = 0; k0 < D_FEAT; k0 += BK) {
    // issue async B stage first: 4 waves x 4 x 1KB = 16KB, in flight during A stage
    {
      const unsigned short* Wk = Wt + k0;
      int nbase = wave * 16 + (lane >> 2);
      int pc = lane & 3;
      for (int i = 0; i < 4; ++i) {
        int n = i * 64 + nbase;
        int cx = pc ^ (n & 3);               // inverse swizzle on source
        gload_lds16(Wk + (size_t)n * D_FEAT + cx * 8,
                    (char*)Bs + i * 4096 + wave * 1024);
      }
    }
    if constexpr (F32IN) {
      const float* X = (const float*)Xv;   // row-major f32 input
      for (int i = 0; i < 2; ++i) {
        int g = t + i * 256;            // 0..511
        int r = g >> 3, c4 = g & 7;
        int grow = row0 + r;
        f32x4 v = (f32x4){0.f, 0.f, 0.f, 0.f};
        if (grow < M) v = *(const f32x4*)(X + (size_t)grow * D_FEAT + k0 + c4 * 4);
        s16x4 b;
        b.x = (short)f2bf(v.x); b.y = (short)f2bf(v.y);
        b.z = (short)f2bf(v.z); b.w = (short)f2bf(v.w);
        *(s16x4*)&As[r * LDR + c4 * 4] = b;
      }
    } else {
      // slice-major bf16 input: k-range [k0,k0+32) == slice k0>>5
      const unsigned short* X = (const unsigned short*)Xv;
      int r = t >> 2, c = t & 3;        // 64 rows x 4 chunks of 8 bf16
      int grow = row0 + r;
      s16x8 v = {0, 0, 0, 0, 0, 0, 0, 0};
      if (grow < M) v = *(const s16x8*)(X + ((size_t)(k0 >> 5) * NP1 + grow) * 32 + c * 8);
      *(s16x8*)&As[r * LDR + c * 8] = v;
    }
    __syncthreads();
    s16x8 a[4], b[4];
    for (int m = 0; m < 4; ++m)
      a[m] = *(const s16x8*)&As[(m * 16 + l15) * LDR + l4 * 8];
    for (int n = 0; n < 4; ++n) {
      int row = wave * 64 + n * 16 + l15;
      int p = l4 ^ (row & 3);              // swizzled read position
      b[n] = *(const s16x8*)((const char*)Bs + row * 64 + p * 16);
    }
    for (int m = 0; m < 4; ++m)
      for (int n = 0; n < 4; ++n)
        acc[m][n] = __builtin_amdgcn_mfma_f32_16x16x32_bf16(a[m], b[n], acc[m][n], 0, 0, 0);
    __syncthreads();
  }

  // epilogue: C/D layout col=lane&15, row=4*(lane>>4)+reg ; write slice-major
  for (int m = 0; m < 4; ++m) {
    int rbase = row0 + m * 16 + l4 * 4;
    for (int r = 0; r < 4; ++r) {
      int row = rbase + r;
      if (row >= M) continue;
      float sc = isd[row];
      for (int n = 0; n < 4; ++n) {
        int col = wave * 64 + n * 16 + l15;
        P[((size_t)(col >> 5) * NP1 + row) * 32 + (col & 31)] = f2bf(acc[m][n][r] * sc);
      }
    }
  }
}

// ---------- aggregation, XCD-sliced, group-per-node, 8-wide ILP (r10 known-good) ----------
__global__ __launch_bounds__(256) void agg_k(const unsigned short* __restrict__ P,
                                             const int* __restrict__ csr,
                                             const int* __restrict__ off,
                                             const float* __restrict__ isd,
                                             const float* __restrict__ bias,
                                             unsigned short* __restrict__ H,
                                             int N, int NP1) {
  int s = blockIdx.x & 7;
  int node = (blockIdx.x >> 3) * 64 + (threadIdx.x >> 2);
  if (node >= N) return;
  int c = threadIdx.x & 3;    // 16B chunk within 64B slice row
  const s16x8* Pb = (const s16x8*)P + (size_t)s * NP1 * 4;

  int lo = off[node], hi = off[node + 1];
  float sc = isd[node];

  float acc[8];
  {
    s16x8 v = Pb[(size_t)node * 4 + c];   // self-loop term
    for (int j = 0; j < 8; ++j) acc[j] = bf2f((unsigned short)v[j]);
  }

  int e = lo;
  if (e + 8 <= hi) {
    i32x4 ia = __builtin_nontemporal_load((const i32x4*)(csr + e));
    i32x4 ib = __builtin_nontemporal_load((const i32x4*)(csr + e + 4));
    for (; e + 8 <= hi; e += 8) {
      i32x4 na = __builtin_nontemporal_load((const i32x4*)(csr + e + 8));   // slack-padded
      i32x4 nb = __builtin_nontemporal_load((const i32x4*)(csr + e + 12));
      s16x8 v0 = Pb[(size_t)ia.x * 4 + c];
      s16x8 v1 = Pb[(size_t)ia.y * 4 + c];
      s16x8 v2 = Pb[(size_t)ia.z * 4 + c];
      s16x8 v3 = Pb[(size_t)ia.w * 4 + c];
      s16x8 v4 = Pb[(size_t)ib.x * 4 + c];
      s16x8 v5 = Pb[(size_t)ib.y * 4 + c];
      s16x8 v6 = Pb[(size_t)ib.z * 4 + c];
      s16x8 v7 = Pb[(size_t)ib.w * 4 + c];
      for (int j = 0; j < 8; ++j) acc[j] += bf2f((unsigned short)v0[j]);
      for (int j = 0; j < 8; ++j) acc[j] += bf2f((unsigned short)v1[j]);
      for (int j = 0; j < 8; ++j) acc[j] += bf2f((unsigned short)v2[j]);
      for (int j = 0; j < 8; ++j) acc[j] += bf2f((unsigned short)v3[j]);
      for (int j = 0; j < 8; ++j) acc[j] += bf2f((unsigned short)v4[j]);
      for (int j = 0; j < 8; ++j) acc[j] += bf2f((unsigned short)v5[j]);
      for (int j = 0; j < 8; ++j) acc[j] += bf2f((unsigned short)v6[j]);
      for (int j = 0; j < 8; ++j) acc[j] += bf2f((unsigned short)v7[j]);
      ia = na; ib = nb;
    }
  }
  if (e < hi) {  // exactly one padded 4-group remains
    i32x4 idx = __builtin_nontemporal_load((const i32x4*)(csr + e));
    s16x8 v0 = Pb[(size_t)idx.x * 4 + c];
    s16x8 v1 = Pb[(size_t)idx.y * 4 + c];
    s16x8 v2 = Pb[(size_t)idx.z * 4 + c];
    s16x8 v3 = Pb[(size_t)idx.w * 4 + c];
    for (int j = 0; j < 8; ++j) acc[j] += bf2f((unsigned short)v0[j]);
    for (int j = 0; j < 8; ++j) acc[j] += bf2f((unsigned short)v1[j]);
    for (int j = 0; j < 8; ++j) acc[j] += bf2f((unsigned short)v2[j]);
    for (int j = 0; j < 8; ++j) acc[j] += bf2f((unsigned short)v3[j]);
  }

  const float* bp = bias + s * 32 + c * 8;
  f32x4 b0 = *(const f32x4*)bp;
  f32x4 b1 = *(const f32x4*)(bp + 4);
  s16x8 o;
  o[0] = (short)f2bf(fmaxf(acc[0] * sc + b0.x, 0.f));
  o[1] = (short)f2bf(fmaxf(acc[1] * sc + b0.y, 0.f));
  o[2] = (short)f2bf(fmaxf(acc[2] * sc + b0.z, 0.f));
  o[3] = (short)f2bf(fmaxf(acc[3] * sc + b0.w, 0.f));
  o[4] = (short)f2bf(fmaxf(acc[4] * sc + b1.x, 0.f));
  o[5] = (short)f2bf(fmaxf(acc[5] * sc + b1.y, 0.f));
  o[6] = (short)f2bf(fmaxf(acc[6] * sc + b1.z, 0.f));
  o[7] = (short)f2bf(fmaxf(acc[7] * sc + b1.w, 0.f));
  __builtin_nontemporal_store(o, (s16x8*)H + ((size_t)s * NP1 + node) * 4 + c);
}

// ---------- pooling (slice-major H) ----------
__device__ __forceinline__ int lower_bound_batch(const int* __restrict__ b, int N, int v) {
  int lo = 0, hi = N;
  while (lo < hi) { int mid = (lo + hi) >> 1; if (b[mid] < v) lo = mid + 1; else hi = mid; }
  return lo;
}

__global__ __launch_bounds__(256) void pool_k(const unsigned short* __restrict__ H,
                                              const int* __restrict__ batch,
                                              float* __restrict__ pp, int N, int NP1) {
  int g = blockIdx.x >> 3;
  int s = blockIdx.x & (NSPLIT - 1);
  int cf = threadIdx.x;  // feature 0..255
  const unsigned short* Hs = H + (size_t)(cf >> 5) * NP1 * 32 + (cf & 31);
  int lo = lower_bound_batch(batch, N, g);
  int hi = lower_bound_batch(batch, N, g + 1);
  int len = hi - lo;
  int slo = lo + (int)(((long long)len * s) >> 3);
  int shi = lo + (int)(((long long)len * (s + 1)) >> 3);
  float sum = 0.f;
  for (int i = slo; i < shi; ++i) sum += bf2f(Hs[(size_t)i * 32]);
  pp[(g * NSPLIT + s) * D_FEAT + cf] = sum;
}

// ---------- FC head ----------
__global__ __launch_bounds__(256) void fc_k(const float* __restrict__ pp,
                                            const int* __restrict__ batch,
                                            const float* __restrict__ fc1w, const float* __restrict__ fc1b,
                                            const float* __restrict__ fc2w, const float* __restrict__ fc2b,
                                            float* __restrict__ out, int N) {
  __shared__ float pl[D_FEAT];
  __shared__ float h1[D_FEAT];
  int g = blockIdx.x, j = threadIdx.x;
  int lo = lower_bound_batch(batch, N, g);
  int hi = lower_bound_batch(batch, N, g + 1);
  float cnt = fmaxf((float)(hi - lo), 1.f);
  float sum = 0.f;
  for (int s = 0; s < NSPLIT; ++s) sum += pp[(g * NSPLIT + s) * D_FEAT + j];
  pl[j] = sum / cnt;
  __syncthreads();
  float a = fc1b[j];
  for (int k = 0; k < D_FEAT; ++k) a += pl[k] * fc1w[k * D_FEAT + j];
  h1[j] = fmaxf(a, 0.f);
  __syncthreads();
  if (j < 128) {
    float o = fc2b[j];
    for (int k = 0; k < D_FEAT; ++k) o += h1[k] * fc2w[k * 128 + j];
    out[g * 128 + j] = o;
  }
}

extern "C" void kernel_launch(void* const* d_in, const int* in_sizes, int n_in,
                              void* d_out, int out_size, void* d_ws, size_t ws_size,
                              hipStream_t stream) {
  const float* x    = (const float*)d_in[0];
  const int*   ei   = (const int*)d_in[1];
  const int*   batch= (const int*)d_in[2];
  const float* W0   = (const float*)d_in[3];
  const float* b0   = (const float*)d_in[4];
  const float* W1   = (const float*)d_in[5];
  const float* b1   = (const float*)d_in[6];
  const float* W2   = (const float*)d_in[7];
  const float* b2   = (const float*)d_in[8];
  const float* fc1w = (const float*)d_in[9];
  const float* fc1b = (const float*)d_in[10];
  const float* fc2w = (const float*)d_in[11];
  const float* fc2b = (const float*)d_in[12];
  float* out = (float*)d_out;

  int N = in_sizes[0] / D_FEAT;   // 50000
  int E = in_sizes[1] / 2;        // 800000
  const int* srcE = ei;
  const int* dstE = ei + E;
  int nb = (N + SCAN_CHUNK - 1) / SCAN_CHUNK;  // 49
  int NP1 = N + 1;                 // +1 sentinel row per slice
  int csize = E + 3 * N + 64;      // padded CSR upper bound + 8-wide prefetch slack

  // workspace carve
  char* w = (char*)d_ws;
  auto alloc = [&](size_t bytes) { char* p = w; w += (bytes + 255) & ~(size_t)255; return p; };
  int*   counts = (int*)  alloc((size_t)N * 4);
  int*   off    = (int*)  alloc((size_t)(N + 1) * 4);
  int*   cur    = (int*)  alloc((size_t)N * 4);
  float* isd    = (float*)alloc((size_t)N * 4);
  int*   csr    = (int*)  alloc((size_t)csize * 4);
  int*   bsum   = (int*)  alloc((size_t)nb * 4);
  int*   boff   = (int*)  alloc((size_t)nb * 4);
  unsigned short* Wt = (unsigned short*)alloc((size_t)3 * 65536 * 2);
  unsigned short* P = (unsigned short*)alloc((size_t)NP1 * D_FEAT * 2);  // slice-major
  unsigned short* H = (unsigned short*)alloc((size_t)NP1 * D_FEAT * 2);  // slice-major
  float* pp     = (float*)alloc((size_t)NGRAPH * NSPLIT * D_FEAT * 4);

  hipMemsetAsync(counts, 0, (size_t)N * 4, stream);
  hist_k<<<(E + 255) / 256, 256, 0, stream>>>(dstE, counts, E);
  bsum_k<<<nb, 256, 0, stream>>>(counts, bsum, N);
  bscan_k<<<1, 1024, 0, stream>>>(bsum, boff, off + N, nb);
  fillscan_k<<<nb, 256, 0, stream>>>(counts, boff, off, cur, isd, N);
  fill_k<<<(E + 255) / 256, 256, 0, stream>>>(srcE, dstE, cur, csr, E);
  padfix_k<<<(N + 256) / 256, 256, 0, stream>>>(counts, off, csr,
      (unsigned int*)P, (unsigned int*)H, NP1, N);
  wconv_k<<<768, 256, 0, stream>>>(W0, W1, W2, Wt);

  int gblocks = (N + BM - 1) / BM;
  int ablocks = 8 * ((N + 63) / 64);

  gemm_k<true> <<<gblocks, 256, 0, stream>>>(x, Wt,             P, isd, N, NP1);
  agg_k        <<<ablocks, 256, 0, stream>>>(P, csr, off, isd, b0, H, N, NP1);
  gemm_k<false><<<gblocks, 256, 0, stream>>>(H, Wt + 65536,     P, isd, N, NP1);
  agg_k        <<<ablocks, 256, 0, stream>>>(P, csr, off, isd, b1, H, N, NP1);
  gemm_k<false><<<gblocks, 256, 0, stream>>>(H, Wt + 2 * 65536, P, isd, N, NP1);
  agg_k        <<<ablocks, 256, 0, stream>>>(P, csr, off, isd, b2, H, N, NP1);

  pool_k<<<NGRAPH * NSPLIT, 256, 0, stream>>>(H, batch, pp, N, NP1);
  fc_k  <<<NGRAPH, 256, 0, stream>>>(pp, batch, fc1w, fc1b, fc2w, fc2b, out, N);
}